// Round 1
// baseline (482.267 us; speedup 1.0000x reference)
//
#include <hip/hip_runtime.h>
#include <hip/hip_bf16.h>

// Fused SE(3) feedforward, bf16 MFMA, fp32 accumulate.
// Per degree: out[bn,d,mm] = sum_h gelu-gated(h) * w_out[h,d],
//             h[bn,hid,mm] = sum_d x[bn,d,mm]*w_in[d,hid], gate couples the mm-group.

typedef __attribute__((ext_vector_type(8))) short short8;   // 8 bf16 = 4 VGPRs (MFMA A/B frag)
typedef __attribute__((ext_vector_type(4))) float f32x4;    // MFMA C/D frag

static __device__ __forceinline__ short f2bf(float f) {
  union { float f; unsigned u; } v; v.f = f;
  unsigned r = v.u + 0x7fffu + ((v.u >> 16) & 1u);  // RNE
  return (short)(r >> 16);
}

// ---- weight packing into MFMA-fragment order (bf16) ----
// w_in: [256 d][1024 h] -> frag tile (nt<64, kt<8): elem j of lane l is
//   w_in[kt*32 + (l>>4)*8 + j][nt*16 + (l&15)], flat = ((nt*8+kt)*64+l)*8+j
__global__ void pack_win_k(const float* __restrict__ w, short* __restrict__ p) {
  const int gid = blockIdx.x * 256 + threadIdx.x;  // 32768 total
  const int lane = gid & 63;
  const int tile = gid >> 6;
  const int kt = tile & 7, nt = tile >> 3;
  const int gg = lane >> 4, cc = lane & 15;
  short8 v;
#pragma unroll
  for (int j = 0; j < 8; ++j) {
    const int d = kt * 32 + gg * 8 + j;
    const int h = nt * 16 + cc;
    v[j] = f2bf(w[d * 1024 + h]);
  }
  *reinterpret_cast<short8*>(p + gid * 8) = v;
}

// w_out: [1024 h][256 d] -> frag tile (kt2<32, nt2<16): elem j of lane l is
//   w_out[kt2*32 + (l>>4)*8 + j][nt2*16 + (l&15)], flat = ((kt2*16+nt2)*64+l)*8+j
__global__ void pack_wout_k(const float* __restrict__ w, short* __restrict__ p) {
  const int gid = blockIdx.x * 256 + threadIdx.x;  // 32768 total
  const int lane = gid & 63;
  const int tile = gid >> 6;
  const int nt2 = tile & 15, kt2 = tile >> 4;
  const int gg = lane >> 4, cc = lane & 15;
  short8 v;
#pragma unroll
  for (int j = 0; j < 8; ++j) {
    const int h = kt2 * 32 + gg * 8 + j;
    const int d = nt2 * 16 + cc;
    v[j] = f2bf(w[h * 256 + d]);
  }
  *reinterpret_cast<short8*>(p + gid * 8) = v;
}

// ---- fused main kernel ----
// Tokens t = mm*16 + r (m-major) so the mm-group of a (row,h) pair shares
// (lane, reg) across M-tile accumulators -> norm/gelu fully in-register.
// LDS XOR swizzle: byte ^= (t&7)<<4  (keeps 16B frag reads contiguous, kills
// the stride-512/256 same-bank pattern).
template<int M>
__global__ __launch_bounds__(256, 1)
void ff_se3_kernel(const float* __restrict__ x,
                   const short* __restrict__ wpin,
                   const short* __restrict__ wpout,
                   const float* __restrict__ scale,
                   const float* __restrict__ bias,
                   float* __restrict__ out)
{
  constexpr int T = 16 * M;
  __shared__ short lA[T * 256];  // x tokens bf16, [t][256 d], swizzled
  __shared__ short lH[T * 128];  // gated h chunk bf16, [t][128], swizzled

  const int tid  = threadIdx.x;
  const int lane = tid & 63;
  const int wave = tid >> 6;
  const int g    = lane >> 4;
  const int lc   = lane & 15;
  const long row0 = (long)blockIdx.x * 16;

  // stage x -> lA (read coalesced float4, scatter bf16 into token layout)
  for (int e4 = tid; e4 < 16 * 64 * M; e4 += 256) {
    const int r  = e4 / (64 * M);
    const int o4 = e4 - r * (64 * M);
    const float4 v = *reinterpret_cast<const float4*>(x + (row0 + r) * (256 * M) + o4 * 4);
    const float vv[4] = {v.x, v.y, v.z, v.w};
#pragma unroll
    for (int i = 0; i < 4; ++i) {
      const int flat = o4 * 4 + i;
      const int d  = flat / M;
      const int mm = flat - d * M;
      const int t  = mm * 16 + r;
      const int byte = t * 512 + ((d * 2) ^ ((t & 7) << 4));
      lA[byte >> 1] = f2bf(vv[i]);
    }
  }

  f32x4 acc_out[M][4];
#pragma unroll
  for (int a = 0; a < M; ++a)
#pragma unroll
    for (int b = 0; b < 4; ++b) acc_out[a][b] = (f32x4)(0.f);

  __syncthreads();

  for (int c = 0; c < 8; ++c) {
    // GEMM1: chunk cols [c*128, +128); this wave owns 32 cols (2 n-tiles)
    f32x4 acc1[M][2];
#pragma unroll
    for (int a = 0; a < M; ++a) { acc1[a][0] = (f32x4)(0.f); acc1[a][1] = (f32x4)(0.f); }
#pragma unroll
    for (int kt = 0; kt < 8; ++kt) {
      short8 af[M];
#pragma unroll
      for (int mm = 0; mm < M; ++mm) {
        const int t = mm * 16 + lc;
        const int byte = t * 512 + (((kt * 32 + g * 8) * 2) ^ ((t & 7) << 4));
        af[mm] = *reinterpret_cast<const short8*>(&lA[byte >> 1]);
      }
      short8 bf[2];
#pragma unroll
      for (int nn = 0; nn < 2; ++nn) {
        const int ntg = c * 8 + wave * 2 + nn;
        bf[nn] = *reinterpret_cast<const short8*>(wpin + ((ntg * 8 + kt) * 64 + lane) * 8);
      }
#pragma unroll
      for (int mm = 0; mm < M; ++mm)
#pragma unroll
        for (int nn = 0; nn < 2; ++nn)
          acc1[mm][nn] = __builtin_amdgcn_mfma_f32_16x16x32_bf16(af[mm], bf[nn], acc1[mm][nn], 0, 0, 0);
    }

    __syncthreads();  // previous chunk's lH consumers are done

    // nonlinearity (per (row,h): norm over mm, exact gelu gate) + write lH
#pragma unroll
    for (int nn = 0; nn < 2; ++nn) {
      const int hgl = c * 128 + wave * 32 + nn * 16 + lc;
      const float sc = scale[hgl];
      const float bi = bias[hgl];
#pragma unroll
      for (int reg = 0; reg < 4; ++reg) {
        float ns = 0.f;
#pragma unroll
        for (int mm = 0; mm < M; ++mm) ns += acc1[mm][nn][reg] * acc1[mm][nn][reg];
        const float nrm = fmaxf(sqrtf(ns), 1e-12f);
        const float z = nrm * sc + bi;
        const float gate = 0.5f * z * (1.f + erff(z * 0.70710678118654752f));
        const float fac = gate / nrm;
        const int tl = g * 4 + reg;          // C-layout row
        const int col = wave * 32 + nn * 16 + lc;
#pragma unroll
        for (int mm = 0; mm < M; ++mm) {
          const int t = mm * 16 + tl;
          const int byte = t * 256 + ((col * 2) ^ ((t & 7) << 4));
          lH[byte >> 1] = f2bf(acc1[mm][nn][reg] * fac);
        }
      }
    }

    __syncthreads();

    // GEMM2 partial: acc_out[T, wave's 64 d-cols] += hg[T,128] @ w_out[chunk,256]
#pragma unroll
    for (int kk = 0; kk < 4; ++kk) {
      short8 a2[M];
#pragma unroll
      for (int mm = 0; mm < M; ++mm) {
        const int t = mm * 16 + lc;
        const int byte = t * 256 + (((kk * 32 + g * 8) * 2) ^ ((t & 7) << 4));
        a2[mm] = *reinterpret_cast<const short8*>(&lH[byte >> 1]);
      }
      short8 b2[4];
#pragma unroll
      for (int nn = 0; nn < 4; ++nn) {
        const int tile = (c * 4 + kk) * 16 + wave * 4 + nn;
        b2[nn] = *reinterpret_cast<const short8*>(wpout + (tile * 64 + lane) * 8);
      }
#pragma unroll
      for (int mm = 0; mm < M; ++mm)
#pragma unroll
        for (int nn = 0; nn < 4; ++nn)
          acc_out[mm][nn] = __builtin_amdgcn_mfma_f32_16x16x32_bf16(a2[mm], b2[nn], acc_out[mm][nn], 0, 0, 0);
    }
  }

  // epilogue: C-layout (col=lane&15, row=(lane>>4)*4+reg), token = mm*16+row
#pragma unroll
  for (int mm = 0; mm < M; ++mm)
#pragma unroll
    for (int nn = 0; nn < 4; ++nn) {
      const int d = wave * 64 + nn * 16 + lc;
#pragma unroll
      for (int reg = 0; reg < 4; ++reg) {
        const int r = g * 4 + reg;
        out[((row0 + r) * 256 + d) * M + mm] = acc_out[mm][nn][reg];
      }
    }
}

extern "C" void kernel_launch(void* const* d_in, const int* in_sizes, int n_in,
                              void* d_out, int out_size, void* d_ws, size_t ws_size,
                              hipStream_t stream)
{
  // d_in order per setup_inputs: (x, w_in, scale, bias, w_out) x degree 0..2
  short* ws = (short*)d_ws;                 // needs 6 * 512KB = 3MB
  const size_t WSZ = 256 * 1024;            // shorts per packed matrix
  float* outf = (float*)d_out;
  const size_t out_off[3] = {0, 4194304, 16777216};  // y0|y1|y2 concat (m=1,3,5)

  for (int dg = 0; dg < 3; ++dg) {
    const float* w_in  = (const float*)d_in[5 * dg + 1];
    const float* w_out = (const float*)d_in[5 * dg + 4];
    pack_win_k <<<128, 256, 0, stream>>>(w_in,  ws + (2 * dg) * WSZ);
    pack_wout_k<<<128, 256, 0, stream>>>(w_out, ws + (2 * dg + 1) * WSZ);
  }
  for (int dg = 0; dg < 3; ++dg) {
    const float* x  = (const float*)d_in[5 * dg + 0];
    const float* sc = (const float*)d_in[5 * dg + 2];
    const float* bi = (const float*)d_in[5 * dg + 3];
    const short* pin  = ws + (2 * dg) * WSZ;
    const short* pout = ws + (2 * dg + 1) * WSZ;
    float* o = outf + out_off[dg];
    switch (dg) {
      case 0: ff_se3_kernel<1><<<1024, 256, 0, stream>>>(x, pin, pout, sc, bi, o); break;
      case 1: ff_se3_kernel<3><<<1024, 256, 0, stream>>>(x, pin, pout, sc, bi, o); break;
      case 2: ff_se3_kernel<5><<<1024, 256, 0, stream>>>(x, pin, pout, sc, bi, o); break;
    }
  }
}